// Round 1
// baseline (13572.044 us; speedup 1.0000x reference)
//
#include <hip/hip_runtime.h>

#define MAPN 250000      // 500*500
#define NPIX 2097152     // 1024*2048
#define FC 64

// ---------------- input-format helpers ----------------
// mask type: 0=int32, 1=uint8, 2=float32, 3=int64
__device__ inline int read_mask(const void* p, int i, int t){
  if (t==0) return ((const int*)p)[i] != 0;
  if (t==1) return ((const unsigned char*)p)[i] != 0;
  if (t==3) return ((const long long*)p)[i] != 0;
  return ((const float*)p)[i] != 0.0f;
}
// idx type: 0=int32, 1=int64
__device__ inline int read_idx(const void* p, int i, int t){
  if (t==1) return (int)((const long long*)p)[i];
  return ((const int*)p)[i];
}

__global__ void detect_kernel(const int* __restrict__ mask_w, const int* __restrict__ idx_w,
                              int* __restrict__ flags){
  int tid = threadIdx.x;
  int orv=0, modd=0, inz=0;
  for (int i=tid;i<4096;i+=256) orv |= mask_w[i];
  for (int i=tid;i<2048;i+=256) modd += (mask_w[2*i+1]!=0);
  for (int i=tid;i<2048;i+=256) inz  += (idx_w[2*i+1]!=0);
  __shared__ int sOr[256], sM[256], sI[256];
  sOr[tid]=orv; sM[tid]=modd; sI[tid]=inz; __syncthreads();
  for (int o=128;o;o>>=1){ if(tid<o){ sOr[tid]|=sOr[tid+o]; sM[tid]+=sM[tid+o]; sI[tid]+=sI[tid+o]; } __syncthreads(); }
  if (tid==0){
    int o = sOr[0];
    int mt;
    if ((o & ~1) == 0)               mt = (sM[0] > 0) ? 0 : 3;  // words all 0/1
    else if ((o & ~0x01010101) == 0) mt = 1;                    // packed bytes 0/1
    else                             mt = 2;                    // float 1.0f pattern
    flags[0] = mt;
    flags[1] = (sI[0] > 0) ? 0 : 1;  // all sampled odd words zero -> int64
  }
}

// ---------------- feature transpose CHW -> HWC ----------------
__global__ void feat_transpose(const float* __restrict__ f, float* __restrict__ out){
  __shared__ float tile[64][65];
  int tid = threadIdx.x;
  int y = blockIdx.y;
  int x0 = blockIdx.x * 64;
  #pragma unroll
  for (int pass=0; pass<16; pass++){
    int c = pass*4 + (tid>>6);
    int x = x0 + (tid & 63);
    tile[c][tid & 63] = f[(size_t)c*131072 + (size_t)y*512 + x];
  }
  __syncthreads();
  #pragma unroll
  for (int pass=0; pass<16; pass++){
    int xl = pass*4 + (tid>>6);
    int c  = tid & 63;
    out[((size_t)y*512 + x0 + xl)*64 + c] = tile[c][xl];
  }
}

// ---------------- mask compaction scan (2M elems, 2048 blocks x 1024 elems) ----------------
__global__ void scan_count(const void* __restrict__ mask, const int* __restrict__ flags,
                           int* __restrict__ blkSums){
  int t = flags[0];
  int tid = threadIdx.x;
  int base = blockIdx.x*1024 + tid*4;
  int s = 0;
  #pragma unroll
  for (int j=0;j<4;j++) s += read_mask(mask, base+j, t);
  __shared__ int red[256];
  red[tid] = s; __syncthreads();
  for (int o=128;o;o>>=1){ if (tid<o) red[tid]+=red[tid+o]; __syncthreads(); }
  if (tid==0) blkSums[blockIdx.x] = red[0];
}

__global__ void scan_offsets(const int* __restrict__ blkSums, int* __restrict__ blkOffs){
  __shared__ int tsum[256];
  int tid = threadIdx.x;
  int loc[8]; int s=0;
  #pragma unroll
  for (int j=0;j<8;j++){ loc[j]=blkSums[tid*8+j]; s+=loc[j]; }
  tsum[tid]=s; __syncthreads();
  for (int o=1;o<256;o<<=1){
    int v = (tid>=o)? tsum[tid-o] : 0;
    __syncthreads();
    tsum[tid] += v;
    __syncthreads();
  }
  int run = tsum[tid]-s;
  #pragma unroll
  for (int j=0;j<8;j++){ blkOffs[tid*8+j]=run; run+=loc[j]; }
  if (tid==255) blkOffs[2048]=run;   // total inliers
}

__global__ void build_table(const void* __restrict__ mask, const int* __restrict__ flags,
                            const int* __restrict__ blkOffs, int* __restrict__ table){
  int t = flags[0];
  int tid = threadIdx.x;
  int base = blockIdx.x*1024 + tid*4;
  int mv[4]; int s=0;
  #pragma unroll
  for (int j=0;j<4;j++){ mv[j]=read_mask(mask, base+j, t); s+=mv[j]; }
  __shared__ int red[256];
  red[tid]=s; __syncthreads();
  for (int o=1;o<256;o<<=1){
    int v = (tid>=o)? red[tid-o] : 0;
    __syncthreads();
    red[tid]+=v;
    __syncthreads();
  }
  int excl = red[tid]-s + blkOffs[blockIdx.x];
  int total = blkOffs[2048];
  #pragma unroll
  for (int j=0;j<4;j++){
    int p = base+j;
    int pos;
    if (mv[j]){ pos = excl; excl++; }
    else      { pos = total + (p - excl); }
    table[pos] = p;
  }
}

// ---------------- max(idx) ----------------
__global__ void max_idx_kernel(const void* __restrict__ idxp, const int* __restrict__ flags,
                               int* __restrict__ mx){
  int t = flags[1];
  int m = 0;
  for (int i = blockIdx.x*blockDim.x + threadIdx.x; i < MAPN; i += gridDim.x*blockDim.x)
    m = max(m, read_idx(idxp, i, t));
  #pragma unroll
  for (int o=32;o;o>>=1) m = max(m, __shfl_down(m, o));
  if ((threadIdx.x & 63) == 0) atomicMax(mx, m);
}

// ---------------- gather + on-the-fly bilinear ----------------
__global__ void gather_kernel(const void* __restrict__ idxp, const int* __restrict__ flags,
                              const int* __restrict__ mxp, const int* __restrict__ table,
                              const float* __restrict__ Fhwc, const float* __restrict__ rgb,
                              float* __restrict__ memory, float* __restrict__ out_obs,
                              float* __restrict__ out_rgb){
  int cell = blockIdx.x*4 + (threadIdx.x>>6);
  int lane = threadIdx.x & 63;
  int t = flags[1];
  int mx = *mxp;
  int idx = read_idx(idxp, cell, t);
  bool m = idx < mx;
  float v = 0.0f, r = 0.0f;
  if (m){
    int p = table[idx];
    int py = p >> 11, px = p & 2047;
    float fy = py * (255.0f/1023.0f);
    int y0 = (int)fy; float wy = fy - (float)y0; int y1 = min(y0+1, 255);
    float fx = px * (511.0f/2047.0f);
    int x0 = (int)fx; float wx = fx - (float)x0; int x1 = min(x0+1, 511);
    const float* f00 = Fhwc + ((size_t)y0*512 + x0)*64;
    const float* f01 = Fhwc + ((size_t)y0*512 + x1)*64;
    const float* f10 = Fhwc + ((size_t)y1*512 + x0)*64;
    const float* f11 = Fhwc + ((size_t)y1*512 + x1)*64;
    float w00=(1.0f-wy)*(1.0f-wx), w01=(1.0f-wy)*wx, w10=wy*(1.0f-wx), w11=wy*wx;
    v = w00*f00[lane] + w01*f01[lane] + w10*f10[lane] + w11*f11[lane];
    if (lane < 3) r = rgb[(size_t)p*3 + lane];
  }
  memory[(size_t)cell*64 + lane] = v;
  if (lane == 0) out_obs[cell] = m ? 1.0f : 0.0f;
  if (lane < 3)  out_rgb[(size_t)cell*3 + lane] = r;
}

// ---------------- weight transpose OIHW -> HWIO ----------------
__global__ void wtrans(const float* __restrict__ w, float* __restrict__ out, int O, int I, int KK){
  int n = O*I*KK;
  for (int e = blockIdx.x*blockDim.x + threadIdx.x; e < n; e += gridDim.x*blockDim.x){
    int o = e/(I*KK); int rem = e - o*I*KK; int i = rem/KK; int k = rem - i*KK;
    out[((size_t)k*I + i)*O + o] = w[e];
  }
}

// ---------------- direct conv, NHWC in / NHWC out, 8 co per thread ----------------
template<int CI, int CO, int K, int PAD>
__global__ __launch_bounds__(256) void conv_direct(const float* __restrict__ in,
                                                   const float* __restrict__ w,
                                                   float* __restrict__ out){
  const int H=500, W=500;
  int x = blockIdx.x*16 + threadIdx.x;
  int y = blockIdx.y*16 + threadIdx.y;
  if (x >= W || y >= H) return;
  int cog = blockIdx.z*8;
  float acc[8];
  #pragma unroll
  for (int i=0;i<8;i++) acc[i]=0.0f;
  for (int kh=0; kh<K; kh++){
    int iy = y + kh - PAD;
    if ((unsigned)iy >= (unsigned)H) continue;
    for (int kw=0; kw<K; kw++){
      int ix = x + kw - PAD;
      if ((unsigned)ix >= (unsigned)W) continue;
      const float* ip = in + ((size_t)iy*W + ix)*CI;
      const float* wp = w + (size_t)(kh*K + kw)*CI*CO + cog;
      #pragma unroll 4
      for (int ci=0; ci<CI; ci+=4){
        const float4 iv = *(const float4*)(ip + ci);
        const float* wq = wp + (size_t)ci*CO;
        #pragma unroll
        for (int j=0;j<4;j++){
          const float s = (j==0)?iv.x:(j==1)?iv.y:(j==2)?iv.z:iv.w;
          const float4 wa = *(const float4*)(wq + j*CO);
          const float4 wb = *(const float4*)(wq + j*CO + 4);
          acc[0]=fmaf(s,wa.x,acc[0]); acc[1]=fmaf(s,wa.y,acc[1]);
          acc[2]=fmaf(s,wa.z,acc[2]); acc[3]=fmaf(s,wa.w,acc[3]);
          acc[4]=fmaf(s,wb.x,acc[4]); acc[5]=fmaf(s,wb.y,acc[5]);
          acc[6]=fmaf(s,wb.z,acc[6]); acc[7]=fmaf(s,wb.w,acc[7]);
        }
      }
    }
  }
  float* op = out + ((size_t)y*W + x)*CO + cog;
  *(float4*)op     = make_float4(acc[0],acc[1],acc[2],acc[3]);
  *(float4*)(op+4) = make_float4(acc[4],acc[5],acc[6],acc[7]);
}

// ---------------- BN (training stats) ----------------
template<int C>
__global__ void bn_stats(const float* __restrict__ x, float* __restrict__ stats){
  __shared__ float ssum[C], ssq[C];
  for (int i=threadIdx.x;i<C;i+=blockDim.x){ ssum[i]=0.0f; ssq[i]=0.0f; }
  __syncthreads();
  size_t n = (size_t)MAPN*C;
  for (size_t i = (size_t)blockIdx.x*blockDim.x + threadIdx.x; i < n; i += (size_t)gridDim.x*blockDim.x){
    float v = x[i];
    int c = (int)(i % (size_t)C);
    atomicAdd(&ssum[c], v);
    atomicAdd(&ssq[c], v*v);
  }
  __syncthreads();
  for (int i=threadIdx.x;i<C;i+=blockDim.x){
    atomicAdd(&stats[i], ssum[i]);
    atomicAdd(&stats[C+i], ssq[i]);
  }
}

template<int C>
__global__ void bn_finalize(const float* __restrict__ stats, const float* __restrict__ g,
                            const float* __restrict__ b, float* __restrict__ scsh){
  int c = threadIdx.x;
  if (c < C){
    float mean = stats[c]   * (1.0f/(float)MAPN);
    float var  = stats[C+c] * (1.0f/(float)MAPN) - mean*mean;
    float inv  = rsqrtf(var + 1e-5f);
    float sc   = g[c]*inv;
    scsh[c]   = sc;
    scsh[C+c] = b[c] - mean*sc;
  }
}

template<int C>
__global__ void bn_apply(float* __restrict__ x, const float* __restrict__ scsh){
  size_t n = (size_t)MAPN*C;
  for (size_t i = (size_t)blockIdx.x*blockDim.x + threadIdx.x; i < n; i += (size_t)gridDim.x*blockDim.x){
    int c = (int)(i % (size_t)C);
    x[i] = fmaxf(fmaf(x[i], scsh[c], scsh[C+c]), 0.0f);
  }
}

// ---------------- final 1x1 conv + bias, NHWC in -> NCHW out ----------------
__global__ void conv5_kernel(const float* __restrict__ in, const float* __restrict__ w,
                             const float* __restrict__ bias, float* __restrict__ out){
  __shared__ float sw[21*48];
  __shared__ float sb[21];
  for (int i=threadIdx.x;i<1008;i+=256) sw[i]=w[i];
  if (threadIdx.x<21) sb[threadIdx.x]=bias[threadIdx.x];
  __syncthreads();
  int pix = blockIdx.x*256 + threadIdx.x;
  if (pix >= MAPN) return;
  float acc[21];
  #pragma unroll
  for (int i=0;i<21;i++) acc[i]=0.0f;
  const float* ip = in + (size_t)pix*48;
  #pragma unroll 4
  for (int ci=0; ci<48; ci+=4){
    const float4 iv = *(const float4*)(ip + ci);
    #pragma unroll
    for (int j=0;j<4;j++){
      const float s = (j==0)?iv.x:(j==1)?iv.y:(j==2)?iv.z:iv.w;
      #pragma unroll
      for (int co=0;co<21;co++) acc[co]=fmaf(s, sw[co*48+ci+j], acc[co]);
    }
  }
  #pragma unroll
  for (int co=0;co<21;co++) out[(size_t)co*MAPN + pix] = acc[co] + sb[co];
}

// ---------------- host launch ----------------
extern "C" void kernel_launch(void* const* d_in, const int* in_sizes, int n_in,
                              void* d_out, int out_size, void* d_ws, size_t ws_size,
                              hipStream_t stream){
  const float* features = (const float*)d_in[0];
  const void*  proj     = d_in[1];
  const void*  mask     = d_in[2];
  const float* rgb      = (const float*)d_in[3];
  const float* w1 = (const float*)d_in[4];
  const float* g1 = (const float*)d_in[5];
  const float* b1 = (const float*)d_in[6];
  const float* w2 = (const float*)d_in[7];
  const float* g2 = (const float*)d_in[8];
  const float* b2 = (const float*)d_in[9];
  const float* w3 = (const float*)d_in[10];
  const float* g3 = (const float*)d_in[11];
  const float* b3 = (const float*)d_in[12];
  const float* w4 = (const float*)d_in[13];
  const float* g4 = (const float*)d_in[14];
  const float* b4 = (const float*)d_in[15];
  const float* w5 = (const float*)d_in[16];
  const float* b5 = (const float*)d_in[17];

  char* ws = (char*)d_ws;
  size_t off = 0;
  float* regA = (float*)(ws + off); off += (size_t)MAPN*64*4;           // 64 MB: memory / buf2 / buf4
  float* regB = (float*)(ws + off); off += (size_t)MAPN*128*4;          // 128 MB: buf1 / buf3 (Fhwc+table during gather)
  float* Fhwc = regB;                                                    // 32 MB (inside regB)
  int*   table = (int*)((char*)regB + (size_t)8388608*4);                // 8 MB (inside regB)
  float* wh1 = (float*)(ws + off); off += (size_t)49*64*128*4;
  float* wh2 = (float*)(ws + off); off += (size_t)9*128*64*4;
  float* wh3 = (float*)(ws + off); off += (size_t)9*64*48*4;
  float* wh4 = (float*)(ws + off); off += (size_t)9*48*48*4;
  int* blkSums = (int*)(ws + off); off += 2048*4;
  int* blkOffs = (int*)(ws + off); off += 2049*4;
  int* maxidx  = (int*)(ws + off); off += 64;
  int* flags   = (int*)(ws + off); off += 64;
  float* stats = (float*)(ws + off); off += 256*4;
  float* scsh  = (float*)(ws + off); off += 256*4;

  float* out_sem = (float*)d_out;
  float* out_obs = out_sem + (size_t)21*MAPN;
  float* out_rgb = out_obs + MAPN;

  // format detection + feature transpose
  detect_kernel<<<1,256,0,stream>>>((const int*)mask, (const int*)proj, flags);
  feat_transpose<<<dim3(8,256),256,0,stream>>>(features, Fhwc);

  // compaction table
  scan_count<<<2048,256,0,stream>>>(mask, flags, blkSums);
  scan_offsets<<<1,256,0,stream>>>(blkSums, blkOffs);
  build_table<<<2048,256,0,stream>>>(mask, flags, blkOffs, table);

  // max(idx)
  hipMemsetAsync(maxidx, 0, 4, stream);
  max_idx_kernel<<<256,256,0,stream>>>(proj, flags, maxidx);

  // gather -> memory (NHWC, regA), observed, rgb
  gather_kernel<<<62500,256,0,stream>>>(proj, flags, maxidx, table, Fhwc, rgb,
                                        regA, out_obs, out_rgb);

  // weight transposes
  wtrans<<<256,256,0,stream>>>(w1, wh1, 128, 64, 49);
  wtrans<<<256,256,0,stream>>>(w2, wh2, 64, 128, 9);
  wtrans<<<64,256,0,stream>>>(w3, wh3, 48, 64, 9);
  wtrans<<<64,256,0,stream>>>(w4, wh4, 48, 48, 9);

  dim3 blk(16,16);

  // L1: 7x7 64->128
  conv_direct<64,128,7,3><<<dim3(32,32,16),blk,0,stream>>>(regA, wh1, regB);
  hipMemsetAsync(stats, 0, 2*128*4, stream);
  bn_stats<128><<<1024,256,0,stream>>>(regB, stats);
  bn_finalize<128><<<1,128,0,stream>>>(stats, g1, b1, scsh);
  bn_apply<128><<<4096,256,0,stream>>>(regB, scsh);

  // L2: 3x3 128->64
  conv_direct<128,64,3,1><<<dim3(32,32,8),blk,0,stream>>>(regB, wh2, regA);
  hipMemsetAsync(stats, 0, 2*64*4, stream);
  bn_stats<64><<<1024,256,0,stream>>>(regA, stats);
  bn_finalize<64><<<1,64,0,stream>>>(stats, g2, b2, scsh);
  bn_apply<64><<<4096,256,0,stream>>>(regA, scsh);

  // L3: 3x3 64->48
  conv_direct<64,48,3,1><<<dim3(32,32,6),blk,0,stream>>>(regA, wh3, regB);
  hipMemsetAsync(stats, 0, 2*48*4, stream);
  bn_stats<48><<<1024,256,0,stream>>>(regB, stats);
  bn_finalize<48><<<1,64,0,stream>>>(stats, g3, b3, scsh);
  bn_apply<48><<<4096,256,0,stream>>>(regB, scsh);

  // L4: 3x3 48->48
  conv_direct<48,48,3,1><<<dim3(32,32,6),blk,0,stream>>>(regB, wh4, regA);
  hipMemsetAsync(stats, 0, 2*48*4, stream);
  bn_stats<48><<<1024,256,0,stream>>>(regA, stats);
  bn_finalize<48><<<1,64,0,stream>>>(stats, g4, b4, scsh);
  bn_apply<48><<<4096,256,0,stream>>>(regA, scsh);

  // L5: 1x1 48->21 + bias, NCHW out
  conv5_kernel<<<(MAPN+255)/256,256,0,stream>>>(regA, w5, b5, out_sem);
}

// Round 2
// 696.792 us; speedup vs baseline: 19.4779x; 19.4779x over previous
//
#include <hip/hip_runtime.h>

#define MAPN 250000      // 500*500
#define NPIX 2097152     // 1024*2048

typedef unsigned short ushort_t;
typedef __attribute__((ext_vector_type(8))) short short8;
typedef __attribute__((ext_vector_type(4))) float f32x4;

__device__ inline ushort_t f2bf(float f){
  unsigned u = __float_as_uint(f);
  u = (u + 0x7fffu + ((u >> 16) & 1u)) >> 16;
  return (ushort_t)u;
}
__device__ inline float bf2f(ushort_t h){ return __uint_as_float(((unsigned)h) << 16); }

// ---------------- input-format helpers ----------------
// mask type: 0=int32, 1=uint8, 2=float32, 3=int64
__device__ inline int read_mask(const void* p, int i, int t){
  if (t==0) return ((const int*)p)[i] != 0;
  if (t==1) return ((const unsigned char*)p)[i] != 0;
  if (t==3) return ((const long long*)p)[i] != 0;
  return ((const float*)p)[i] != 0.0f;
}
// idx type: 0=int32, 1=int64
__device__ inline int read_idx(const void* p, int i, int t){
  if (t==1) return (int)((const long long*)p)[i];
  return ((const int*)p)[i];
}

__global__ void detect_kernel(const int* __restrict__ mask_w, const int* __restrict__ idx_w,
                              int* __restrict__ flags){
  int tid = threadIdx.x;
  int orv=0, modd=0, inz=0;
  for (int i=tid;i<4096;i+=256) orv |= mask_w[i];
  for (int i=tid;i<2048;i+=256) modd += (mask_w[2*i+1]!=0);
  for (int i=tid;i<2048;i+=256) inz  += (idx_w[2*i+1]!=0);
  __shared__ int sOr[256], sM[256], sI[256];
  sOr[tid]=orv; sM[tid]=modd; sI[tid]=inz; __syncthreads();
  for (int o=128;o;o>>=1){ if(tid<o){ sOr[tid]|=sOr[tid+o]; sM[tid]+=sM[tid+o]; sI[tid]+=sI[tid+o]; } __syncthreads(); }
  if (tid==0){
    int o = sOr[0];
    int mt;
    if ((o & ~1) == 0)               mt = (sM[0] > 0) ? 0 : 3;
    else if ((o & ~0x01010101) == 0) mt = 1;
    else                             mt = 2;
    flags[0] = mt;
    flags[1] = (sI[0] > 0) ? 0 : 1;
  }
}

// ---------------- feature transpose CHW -> HWC (fp32 -> bf16) ----------------
__global__ void feat_transpose(const float* __restrict__ f, ushort_t* __restrict__ out){
  __shared__ float tile[64][65];
  int tid = threadIdx.x;
  int y = blockIdx.y;
  int x0 = blockIdx.x * 64;
  #pragma unroll
  for (int pass=0; pass<16; pass++){
    int c = pass*4 + (tid>>6);
    int x = x0 + (tid & 63);
    tile[c][tid & 63] = f[(size_t)c*131072 + (size_t)y*512 + x];
  }
  __syncthreads();
  #pragma unroll
  for (int pass=0; pass<16; pass++){
    int xl = pass*4 + (tid>>6);
    int c  = tid & 63;
    out[((size_t)y*512 + x0 + xl)*64 + c] = f2bf(tile[c][xl]);
  }
}

// ---------------- mask compaction scan ----------------
__global__ void scan_count(const void* __restrict__ mask, const int* __restrict__ flags,
                           int* __restrict__ blkSums){
  int t = flags[0];
  int tid = threadIdx.x;
  int base = blockIdx.x*1024 + tid*4;
  int s = 0;
  #pragma unroll
  for (int j=0;j<4;j++) s += read_mask(mask, base+j, t);
  __shared__ int red[256];
  red[tid] = s; __syncthreads();
  for (int o=128;o;o>>=1){ if (tid<o) red[tid]+=red[tid+o]; __syncthreads(); }
  if (tid==0) blkSums[blockIdx.x] = red[0];
}

__global__ void scan_offsets(const int* __restrict__ blkSums, int* __restrict__ blkOffs){
  __shared__ int tsum[256];
  int tid = threadIdx.x;
  int loc[8]; int s=0;
  #pragma unroll
  for (int j=0;j<8;j++){ loc[j]=blkSums[tid*8+j]; s+=loc[j]; }
  tsum[tid]=s; __syncthreads();
  for (int o=1;o<256;o<<=1){
    int v = (tid>=o)? tsum[tid-o] : 0;
    __syncthreads();
    tsum[tid] += v;
    __syncthreads();
  }
  int run = tsum[tid]-s;
  #pragma unroll
  for (int j=0;j<8;j++){ blkOffs[tid*8+j]=run; run+=loc[j]; }
  if (tid==255) blkOffs[2048]=run;
}

__global__ void build_table(const void* __restrict__ mask, const int* __restrict__ flags,
                            const int* __restrict__ blkOffs, int* __restrict__ table){
  int t = flags[0];
  int tid = threadIdx.x;
  int base = blockIdx.x*1024 + tid*4;
  int mv[4]; int s=0;
  #pragma unroll
  for (int j=0;j<4;j++){ mv[j]=read_mask(mask, base+j, t); s+=mv[j]; }
  __shared__ int red[256];
  red[tid]=s; __syncthreads();
  for (int o=1;o<256;o<<=1){
    int v = (tid>=o)? red[tid-o] : 0;
    __syncthreads();
    red[tid]+=v;
    __syncthreads();
  }
  int excl = red[tid]-s + blkOffs[blockIdx.x];
  int total = blkOffs[2048];
  #pragma unroll
  for (int j=0;j<4;j++){
    int p = base+j;
    int pos;
    if (mv[j]){ pos = excl; excl++; }
    else      { pos = total + (p - excl); }
    table[pos] = p;
  }
}

// ---------------- max(idx) ----------------
__global__ void max_idx_kernel(const void* __restrict__ idxp, const int* __restrict__ flags,
                               int* __restrict__ mx){
  int t = flags[1];
  int m = 0;
  for (int i = blockIdx.x*blockDim.x + threadIdx.x; i < MAPN; i += gridDim.x*blockDim.x)
    m = max(m, read_idx(idxp, i, t));
  #pragma unroll
  for (int o=32;o;o>>=1) m = max(m, __shfl_down(m, o));
  if ((threadIdx.x & 63) == 0) atomicMax(mx, m);
}

// ---------------- gather + on-the-fly bilinear (bf16 in/out) ----------------
__global__ void gather_kernel(const void* __restrict__ idxp, const int* __restrict__ flags,
                              const int* __restrict__ mxp, const int* __restrict__ table,
                              const ushort_t* __restrict__ Fhwc, const float* __restrict__ rgb,
                              ushort_t* __restrict__ memory, float* __restrict__ out_obs,
                              float* __restrict__ out_rgb){
  int cell = blockIdx.x*4 + (threadIdx.x>>6);
  int lane = threadIdx.x & 63;
  int t = flags[1];
  int mx = *mxp;
  int idx = read_idx(idxp, cell, t);
  bool m = idx < mx;
  float v = 0.0f, r = 0.0f;
  if (m){
    int p = table[idx];
    int py = p >> 11, px = p & 2047;
    float fy = py * (255.0f/1023.0f);
    int y0 = (int)fy; float wy = fy - (float)y0; int y1 = min(y0+1, 255);
    float fx = px * (511.0f/2047.0f);
    int x0 = (int)fx; float wx = fx - (float)x0; int x1 = min(x0+1, 511);
    const ushort_t* f00 = Fhwc + ((size_t)y0*512 + x0)*64;
    const ushort_t* f01 = Fhwc + ((size_t)y0*512 + x1)*64;
    const ushort_t* f10 = Fhwc + ((size_t)y1*512 + x0)*64;
    const ushort_t* f11 = Fhwc + ((size_t)y1*512 + x1)*64;
    float w00=(1.0f-wy)*(1.0f-wx), w01=(1.0f-wy)*wx, w10=wy*(1.0f-wx), w11=wy*wx;
    v = w00*bf2f(f00[lane]) + w01*bf2f(f01[lane]) + w10*bf2f(f10[lane]) + w11*bf2f(f11[lane]);
    if (lane < 3) r = rgb[(size_t)p*3 + lane];
  }
  memory[(size_t)cell*64 + lane] = f2bf(v);
  if (lane == 0) out_obs[cell] = m ? 1.0f : 0.0f;
  if (lane < 3)  out_rgb[(size_t)cell*3 + lane] = r;
}

// ---------------- weight prep: OIHW fp32 -> [O][KK][CIPAD] bf16 (ci zero-padded) ----------------
__global__ void wprep(const float* __restrict__ w, ushort_t* __restrict__ out,
                      int O, int I, int KK, int CIPAD){
  int n = O*KK*CIPAD;
  for (int e = blockIdx.x*blockDim.x + threadIdx.x; e < n; e += gridDim.x*blockDim.x){
    int o = e/(KK*CIPAD); int r = e - o*KK*CIPAD; int k = r/CIPAD; int ci = r - k*CIPAD;
    float v = (ci < I) ? w[((size_t)o*I + ci)*KK + k] : 0.0f;
    out[e] = f2bf(v);
  }
}

// ---------------- MFMA implicit-GEMM conv (shift-GEMM over kh,kw) ----------------
// in:  bf16 NHWC [MAPN][CI]   (CI = padded input channels)
// wt:  bf16 [CO][KS*KS][CI]
// out: bf16 NHWC [MAPN][COPAD], writes only c<CO columns
// partials: fp32 [nblk][2*CO] block-level (sum, sumsq) per channel
template<int CI, int CO, int COPAD, int KS, int PAD>
__global__ __launch_bounds__(256) void conv_mfma(const ushort_t* __restrict__ in,
                                                 const ushort_t* __restrict__ wt,
                                                 ushort_t* __restrict__ out,
                                                 float* __restrict__ partials){
  constexpr int NF  = CO/16;        // n-fragments per wave
  constexpr int CIG = CI/8;         // 8-channel chunks per pixel
  constexpr int AIT = (128*CIG)/256;
  constexpr int BCH = CO*CIG;
  constexpr int BIT = (BCH+255)/256;
  __shared__ char sA[128*CI*2];
  __shared__ char sB[CO*CI*2];
  __shared__ float sStat[4][NF][16][2];

  int tid = threadIdx.x;
  int wv = tid >> 6, lane = tid & 63;
  int p0 = blockIdx.x * 128;

  int ay[AIT], ax[AIT];
  #pragma unroll
  for (int i=0;i<AIT;i++){
    int c = i*256 + tid;
    int pix = c / CIG;
    int p = p0 + pix;
    int y = (int)((unsigned)p / 500u);
    ay[i]=y; ax[i]=p - y*500;
  }

  f32x4 acc[2][NF];
  #pragma unroll
  for (int mi=0;mi<2;mi++)
    #pragma unroll
    for (int ni=0;ni<NF;ni++) acc[mi][ni] = (f32x4)0.0f;

  for (int t=0; t<KS*KS; t++){
    int kh = t/KS, kw = t%KS;
    int dy = kh-PAD, dx = kw-PAD;
    int off = dy*500 + dx;
    // ---- stage A (shifted, zero-padded) ----
    #pragma unroll
    for (int i=0;i<AIT;i++){
      int c = i*256 + tid;
      int pix = c / CIG, cig8 = (c % CIG)*8;
      int p = p0 + pix;
      int ys = ay[i]+dy, xs = ax[i]+dx;
      bool valid = (p < MAPN) && ((unsigned)ys < 500u) && ((unsigned)xs < 500u);
      uint4 v = make_uint4(0u,0u,0u,0u);
      if (valid) v = *(const uint4*)(in + (size_t)(p+off)*CI + cig8);
      unsigned wa = ((unsigned)(pix*CI + cig8)*2u) ^ ((unsigned)(pix&7)<<4);
      *(uint4*)(sA + wa) = v;
    }
    // ---- stage B ----
    #pragma unroll
    for (int i=0;i<BIT;i++){
      int c = i*256 + tid;
      if ((BCH % 256 == 0) || c < BCH){
        int co = c / CIG, cig8 = (c % CIG)*8;
        uint4 v = *(const uint4*)(wt + ((size_t)co*(KS*KS) + t)*CI + cig8);
        unsigned wb = ((unsigned)(co*CI + cig8)*2u) ^ ((unsigned)(co&7)<<4);
        *(uint4*)(sB + wb) = v;
      }
    }
    __syncthreads();
    #pragma unroll
    for (int kc=0; kc<CI/32; kc++){
      int ciL = kc*32 + (lane>>4)*8;
      short8 af[2];
      #pragma unroll
      for (int mi=0;mi<2;mi++){
        int pix = wv*32 + mi*16 + (lane&15);
        unsigned ra = ((unsigned)(pix*CI + ciL)*2u) ^ ((unsigned)(pix&7)<<4);
        af[mi] = *(const short8*)(sA + ra);
      }
      #pragma unroll
      for (int ni=0;ni<NF;ni++){
        int co = ni*16 + (lane&15);
        unsigned rb = ((unsigned)(co*CI + ciL)*2u) ^ ((unsigned)(co&7)<<4);
        short8 bfr = *(const short8*)(sB + rb);
        acc[0][ni] = __builtin_amdgcn_mfma_f32_16x16x32_bf16(af[0], bfr, acc[0][ni], 0,0,0);
        acc[1][ni] = __builtin_amdgcn_mfma_f32_16x16x32_bf16(af[1], bfr, acc[1][ni], 0,0,0);
      }
    }
    __syncthreads();
  }

  // ---- epilogue: bf16 store + fused BN partial stats ----
  #pragma unroll
  for (int ni=0;ni<NF;ni++){
    float ps=0.f, pq=0.f;
    #pragma unroll
    for (int mi=0;mi<2;mi++){
      int prow = p0 + wv*32 + mi*16 + (lane>>4)*4;
      #pragma unroll
      for (int j=0;j<4;j++){
        float v = acc[mi][ni][j];
        ps += v; pq += v*v;
        int p = prow + j;
        if (p < MAPN) out[(size_t)p*COPAD + ni*16 + (lane&15)] = f2bf(v);
      }
    }
    ps += __shfl_xor(ps, 16); pq += __shfl_xor(pq, 16);
    ps += __shfl_xor(ps, 32); pq += __shfl_xor(pq, 32);
    if (lane < 16){ sStat[wv][ni][lane][0]=ps; sStat[wv][ni][lane][1]=pq; }
  }
  __syncthreads();
  if (tid < CO){
    float s = 0.f, q = 0.f;
    #pragma unroll
    for (int w=0;w<4;w++){ s += sStat[w][tid>>4][tid&15][0]; q += sStat[w][tid>>4][tid&15][1]; }
    partials[(size_t)blockIdx.x*(2*CO) + tid]      = s;
    partials[(size_t)blockIdx.x*(2*CO) + CO + tid] = q;
  }
}

// ---------------- BN: reduce per-block partials -> scale/shift ----------------
template<int CO>
__global__ void bn_reduce(const float* __restrict__ partials, int nblk,
                          const float* __restrict__ g, const float* __restrict__ b,
                          float* __restrict__ scsh){
  int c = blockIdx.x;
  float s=0.f, q=0.f;
  for (int i=threadIdx.x; i<nblk; i+=256){
    s += partials[(size_t)i*(2*CO) + c];
    q += partials[(size_t)i*(2*CO) + CO + c];
  }
  __shared__ float rs[256], rq[256];
  rs[threadIdx.x]=s; rq[threadIdx.x]=q; __syncthreads();
  for (int o=128;o;o>>=1){
    if (threadIdx.x<o){ rs[threadIdx.x]+=rs[threadIdx.x+o]; rq[threadIdx.x]+=rq[threadIdx.x+o]; }
    __syncthreads();
  }
  if (threadIdx.x==0){
    float mean = rs[0]*(1.0f/(float)MAPN);
    float var  = rq[0]*(1.0f/(float)MAPN) - mean*mean;
    float inv  = rsqrtf(var + 1e-5f);
    float sc   = g[c]*inv;
    scsh[c]    = sc;
    scsh[CO+c] = b[c] - mean*sc;
  }
}

// ---------------- BN apply + ReLU, in-place on bf16 NHWC [MAPN][COPAD] ----------------
template<int CO, int COPAD>
__global__ void bn_apply_ip(ushort_t* __restrict__ x, const float* __restrict__ scsh){
  __shared__ float ssc[CO], ssh[CO];
  for (int i=threadIdx.x;i<CO;i+=blockDim.x){ ssc[i]=scsh[i]; ssh[i]=scsh[CO+i]; }
  __syncthreads();
  const int CH = CO/8;
  size_t n = (size_t)MAPN*CH;
  for (size_t e = (size_t)blockIdx.x*blockDim.x + threadIdx.x; e < n; e += (size_t)gridDim.x*blockDim.x){
    size_t p = e / CH; int cg = (int)(e % CH)*8;
    ushort_t* ptr = x + p*COPAD + cg;
    uint4 v = *(uint4*)ptr;
    ushort_t* hv = (ushort_t*)&v;
    #pragma unroll
    for (int j=0;j<8;j++){
      float f = bf2f(hv[j]);
      f = fmaxf(fmaf(f, ssc[cg+j], ssh[cg+j]), 0.0f);
      hv[j] = f2bf(f);
    }
    *(uint4*)ptr = v;
  }
}

// ---------------- final 1x1 conv + bias, bf16 NHWC in -> fp32 NCHW out ----------------
__global__ void conv5_kernel(const ushort_t* __restrict__ in, const float* __restrict__ w,
                             const float* __restrict__ bias, float* __restrict__ out){
  __shared__ float sw[21*48];
  __shared__ float sb[21];
  for (int i=threadIdx.x;i<1008;i+=256) sw[i]=w[i];
  if (threadIdx.x<21) sb[threadIdx.x]=bias[threadIdx.x];
  __syncthreads();
  int pix = blockIdx.x*256 + threadIdx.x;
  if (pix >= MAPN) return;
  float acc[21];
  #pragma unroll
  for (int i=0;i<21;i++) acc[i]=0.0f;
  const ushort_t* ip = in + (size_t)pix*64;
  #pragma unroll
  for (int cg=0; cg<6; cg++){
    uint4 v = *(const uint4*)(ip + cg*8);
    ushort_t* hv = (ushort_t*)&v;
    #pragma unroll
    for (int j=0;j<8;j++){
      float s = bf2f(hv[j]);
      int ci = cg*8+j;
      #pragma unroll
      for (int co=0;co<21;co++) acc[co]=fmaf(s, sw[co*48+ci], acc[co]);
    }
  }
  #pragma unroll
  for (int co=0;co<21;co++) out[(size_t)co*MAPN + pix] = acc[co] + sb[co];
}

// ---------------- host launch ----------------
static inline size_t al256(size_t x){ return (x + 255) & ~(size_t)255; }

extern "C" void kernel_launch(void* const* d_in, const int* in_sizes, int n_in,
                              void* d_out, int out_size, void* d_ws, size_t ws_size,
                              hipStream_t stream){
  const float* features = (const float*)d_in[0];
  const void*  proj     = d_in[1];
  const void*  mask     = d_in[2];
  const float* rgb      = (const float*)d_in[3];
  const float* w1 = (const float*)d_in[4];
  const float* g1 = (const float*)d_in[5];
  const float* b1 = (const float*)d_in[6];
  const float* w2 = (const float*)d_in[7];
  const float* g2 = (const float*)d_in[8];
  const float* b2 = (const float*)d_in[9];
  const float* w3 = (const float*)d_in[10];
  const float* g3 = (const float*)d_in[11];
  const float* b3 = (const float*)d_in[12];
  const float* w4 = (const float*)d_in[13];
  const float* g4 = (const float*)d_in[14];
  const float* b4 = (const float*)d_in[15];
  const float* w5 = (const float*)d_in[16];
  const float* b5 = (const float*)d_in[17];

  const int NBLK = (MAPN + 127)/128;   // 1954

  char* ws = (char*)d_ws;
  size_t off = 0;
  ushort_t* mem_bf = (ushort_t*)(ws + off); off += al256((size_t)MAPN*64*2);
  ushort_t* actA   = (ushort_t*)(ws + off); off += al256((size_t)MAPN*128*2);
  ushort_t* actB   = (ushort_t*)(ws + off); off += al256((size_t)MAPN*64*2);
  ushort_t* Fhwc   = (ushort_t*)(ws + off); off += al256((size_t)131072*64*2);
  int*      table  = (int*)(ws + off);      off += al256((size_t)NPIX*4);
  ushort_t* wh1    = (ushort_t*)(ws + off); off += al256((size_t)128*49*64*2);
  ushort_t* wh2    = (ushort_t*)(ws + off); off += al256((size_t)64*9*128*2);
  ushort_t* wh3    = (ushort_t*)(ws + off); off += al256((size_t)48*9*64*2);
  ushort_t* wh4    = (ushort_t*)(ws + off); off += al256((size_t)48*9*64*2);
  float*    partials = (float*)(ws + off);  off += al256((size_t)NBLK*2*128*4);
  int* blkSums = (int*)(ws + off); off += al256(2048*4);
  int* blkOffs = (int*)(ws + off); off += al256(2049*4);
  int* maxidx  = (int*)(ws + off); off += 256;
  int* flags   = (int*)(ws + off); off += 256;
  float* scsh  = (float*)(ws + off); off += al256(256*4);

  float* out_sem = (float*)d_out;
  float* out_obs = out_sem + (size_t)21*MAPN;
  float* out_rgb = out_obs + MAPN;

  // format detection + feature transpose (fp32 CHW -> bf16 HWC)
  detect_kernel<<<1,256,0,stream>>>((const int*)mask, (const int*)proj, flags);
  feat_transpose<<<dim3(8,256),256,0,stream>>>(features, Fhwc);

  // compaction table
  scan_count<<<2048,256,0,stream>>>(mask, flags, blkSums);
  scan_offsets<<<1,256,0,stream>>>(blkSums, blkOffs);
  build_table<<<2048,256,0,stream>>>(mask, flags, blkOffs, table);

  // max(idx)
  hipMemsetAsync(maxidx, 0, 4, stream);
  max_idx_kernel<<<256,256,0,stream>>>(proj, flags, maxidx);

  // weight prep (independent of the above)
  wprep<<<256,256,0,stream>>>(w1, wh1, 128, 64, 49, 64);
  wprep<<<64,256,0,stream>>>(w2, wh2, 64, 128, 9, 128);
  wprep<<<32,256,0,stream>>>(w3, wh3, 48, 64, 9, 64);
  wprep<<<32,256,0,stream>>>(w4, wh4, 48, 48, 9, 64);

  // gather -> memory (bf16 NHWC), observed, rgb
  gather_kernel<<<62500,256,0,stream>>>(proj, flags, maxidx, table, Fhwc, rgb,
                                        mem_bf, out_obs, out_rgb);

  // L1: 7x7 64->128
  conv_mfma<64,128,128,7,3><<<NBLK,256,0,stream>>>(mem_bf, wh1, actA, partials);
  bn_reduce<128><<<128,256,0,stream>>>(partials, NBLK, g1, b1, scsh);
  bn_apply_ip<128,128><<<2048,256,0,stream>>>(actA, scsh);

  // L2: 3x3 128->64
  conv_mfma<128,64,64,3,1><<<NBLK,256,0,stream>>>(actA, wh2, actB, partials);
  bn_reduce<64><<<64,256,0,stream>>>(partials, NBLK, g2, b2, scsh);
  bn_apply_ip<64,64><<<2048,256,0,stream>>>(actB, scsh);

  // L3: 3x3 64->48 (output padded to 64 ch)
  conv_mfma<64,48,64,3,1><<<NBLK,256,0,stream>>>(actB, wh3, actA, partials);
  bn_reduce<48><<<48,256,0,stream>>>(partials, NBLK, g3, b3, scsh);
  bn_apply_ip<48,64><<<2048,256,0,stream>>>(actA, scsh);

  // L4: 3x3 48(pad64)->48 (output padded to 64 ch)
  conv_mfma<64,48,64,3,1><<<NBLK,256,0,stream>>>(actA, wh4, actB, partials);
  bn_reduce<48><<<48,256,0,stream>>>(partials, NBLK, g4, b4, scsh);
  bn_apply_ip<48,64><<<2048,256,0,stream>>>(actB, scsh);

  // L5: 1x1 48->21 + bias, NCHW out
  conv5_kernel<<<(MAPN+255)/256,256,0,stream>>>(actB, w5, b5, out_sem);
}